// Round 5
// baseline (2945.612 us; speedup 1.0000x reference)
//
#include <hip/hip_runtime.h>
#include <stdint.h>
#include <math.h>

#define B_   32
#define S_   512
#define H_   256
#define M_   (B_*S_)     // 16384 tokens
#define NB   1792        // 7*H
#define C_   5

typedef __bf16 bf16;

__device__ __forceinline__ float sigm(float x){ return 1.f/(1.f+expf(-x)); }

// ---------- wv[m,h] = embed[idx[m], h] ----------
__global__ void gather_k(const int* __restrict__ idx, const float* __restrict__ embed,
                         float* __restrict__ wv){
    int i = blockIdx.x*256 + threadIdx.x;
    wv[i] = embed[(size_t)idx[i>>8]*H_ + (i & 255)];
}

// ---------- out[b,h] = mean_s x[b,s,h] ----------
__global__ void mean_k(const float* __restrict__ x, float* __restrict__ out){
    int b = blockIdx.x, h = threadIdx.x;
    float s = 0.f;
    for (int t=0;t<S_;t++) s += x[((size_t)b*S_ + t)*H_ + h];
    out[b*H_ + h] = s * (1.f/512.f);
}

// ---------- before/after window sums ----------
__global__ void shift2_k(const float* __restrict__ x, float* __restrict__ bef,
                         float* __restrict__ aft){
    int m = blockIdx.x, h = threadIdx.x, s = m & (S_-1);
    size_t i = (size_t)m*H_ + h;
    float b = 0.f, a = 0.f;
    if (s >= 1) b += x[i - H_];
    if (s >= 2) b += x[i - 2*H_];
    if (s <= S_-2) a += x[i + H_];
    if (s <= S_-3) a += x[i + 2*H_];
    bef[i] = b; aft[i] = a;
}

// ---------- f_hat_g (sigmoided), og_g, svg = sv@W_fgi_g.T + b_fgi ----------
__global__ void small_k(const float* __restrict__ sv, const float* __restrict__ avgh,
    const float* __restrict__ Wfg_g, const float* __restrict__ Wfg_h,
    const float* __restrict__ Wog_g, const float* __restrict__ Wog_h,
    const float* __restrict__ Wfgi_g, const float* __restrict__ b_fg,
    const float* __restrict__ gate_bias, const float* __restrict__ b_fgi,
    float* __restrict__ fhg, float* __restrict__ ogg, float* __restrict__ svg){
    int b = blockIdx.x, h = threadIdx.x;
    __shared__ float ssv[H_], sav[H_];
    ssv[h] = sv[b*H_+h]; sav[h] = avgh[b*H_+h];
    __syncthreads();
    float d1=0,d2=0,d3=0,d4=0,d5=0;
    const float* r1 = Wfg_g  + (size_t)h*H_;
    const float* r2 = Wfg_h  + (size_t)h*H_;
    const float* r3 = Wog_g  + (size_t)h*H_;
    const float* r4 = Wog_h  + (size_t)h*H_;
    const float* r5 = Wfgi_g + (size_t)h*H_;
    for (int k=0;k<H_;k++){
        float a = ssv[k], c = sav[k];
        d1 += a*r1[k]; d2 += c*r2[k]; d3 += a*r3[k]; d4 += c*r4[k]; d5 += a*r5[k];
    }
    fhg[b*H_+h] = sigm(d1 + d2 + b_fg[h]);
    ogg[b*H_+h] = sigm(d3 + d4 + gate_bias[5*H_+h]);   // reference uses gate_bias[5] here
    svg[b*H_+h] = d5 + b_fgi[h];
}

// ---------- fgih[m,h] = sum_k hh[m,k]*W_fgi_h[h,k]  (f32) ----------
__global__ __launch_bounds__(256) void gemm_nt_k(const float* __restrict__ A,
                                                 const float* __restrict__ Bw,
                                                 float* __restrict__ C){
    __shared__ float As[64][17];
    __shared__ float Bs[64][17];
    int t = threadIdx.x;
    int n0 = blockIdx.x*64, m0 = blockIdx.y*64;
    int lrow = t >> 2, lq = (t & 3)*4;
    int ty = t >> 4, tx = t & 15;
    float acc[4][4] = {};
    const float* Ap = A  + (size_t)(m0+lrow)*H_;
    const float* Bp = Bw + (size_t)(n0+lrow)*H_;
    for (int k0=0;k0<H_;k0+=16){
        __syncthreads();
        float4 av = *(const float4*)(Ap + k0 + lq);
        float4 bv = *(const float4*)(Bp + k0 + lq);
        As[lrow][lq]=av.x; As[lrow][lq+1]=av.y; As[lrow][lq+2]=av.z; As[lrow][lq+3]=av.w;
        Bs[lrow][lq]=bv.x; Bs[lrow][lq+1]=bv.y; Bs[lrow][lq+2]=bv.z; Bs[lrow][lq+3]=bv.w;
        __syncthreads();
        #pragma unroll
        for (int kk=0;kk<16;kk++){
            float a[4], b[4];
            #pragma unroll
            for (int i=0;i<4;i++) a[i]=As[ty*4+i][kk];
            #pragma unroll
            for (int j=0;j<4;j++) b[j]=Bs[tx*4+j][kk];
            #pragma unroll
            for (int i=0;i<4;i++)
                #pragma unroll
                for (int j=0;j<4;j++) acc[i][j] = fmaf(a[i], b[j], acc[i][j]);
        }
    }
    #pragma unroll
    for (int i=0;i<4;i++)
        #pragma unroll
        for (int j=0;j<4;j++)
            C[(size_t)(m0+ty*4+i)*H_ + (n0+tx*4+j)] = acc[i][j];
}

// ---------- tmp[m,h] = softmax_h(sigmoid(svg + fgih)) * cs[m,h] ----------
__global__ void score_k(const float* __restrict__ fgih, const float* __restrict__ svg,
                        const float* __restrict__ cs, float* __restrict__ tmp){
    int m = blockIdx.x, h = threadIdx.x, b = m >> 9;
    __shared__ float r[256];
    float v = sigm(svg[b*H_+h] + fgih[(size_t)m*H_ + h]);
    float e = expf(v);
    r[h] = e; __syncthreads();
    for (int off=128; off; off>>=1){ if (h<off) r[h] += r[h+off]; __syncthreads(); }
    tmp[(size_t)m*H_ + h] = (e / r[0]) * cs[(size_t)m*H_ + h];
}

// ---------- scsum[b,h] = sum_s tmp[b,s,h] ----------
__global__ void sumS_k(const float* __restrict__ tmp, float* __restrict__ scsum){
    int b = blockIdx.x, h = threadIdx.x;
    float s = 0.f;
    for (int t=0;t<S_;t++) s += tmp[((size_t)b*S_ + t)*H_ + h];
    scsum[b*H_+h] = s;
}

// ---------- new_scs = softmax_h(f_hat_g)*scs + scsum ; new_sv = og_g*tanh(new_scs) ----------
__global__ void newscs_k(const float* __restrict__ fhg, const float* __restrict__ ogg,
                         const float* __restrict__ scs_in, const float* __restrict__ scsum,
                         float* __restrict__ scs_out, float* __restrict__ sv_out){
    int b = blockIdx.x, h = threadIdx.x;
    __shared__ float r[256];
    float e = expf(fhg[b*H_+h]);
    r[h] = e; __syncthreads();
    for (int off=128; off; off>>=1){ if (h<off) r[h] += r[h+off]; __syncthreads(); }
    float ns = (e / r[0]) * scs_in[b*H_+h] + scsum[b*H_+h];
    scs_out[b*H_+h] = ns;
    sv_out[b*H_+h]  = ogg[b*H_+h] * tanhf(ns);
}

// ---------- gt[b, g*256+h] = sum_k new_sv[b,k]*W_g[g,h,k] + gate_bias[g,h] ----------
__global__ void gterm_k(const float* __restrict__ svn, const float* __restrict__ Wg,
                        const float* __restrict__ gbias, float* __restrict__ gt){
    int g = blockIdx.x, b = blockIdx.y, h = threadIdx.x;
    __shared__ float s[H_];
    s[h] = svn[b*H_+h]; __syncthreads();
    const float* w = Wg + ((size_t)g*H_ + h)*H_;
    float d = 0.f;
    for (int k=0;k<H_;k++) d += s[k]*w[k];
    gt[(size_t)b*NB + g*H_ + h] = d + gbias[g*H_+h];
}

// ---------- pre[m, g*256+h] = hb.Wlr[:256] + ha.Wlr[256:] + hh.Wc + wv.Wx + gt ----------
__global__ __launch_bounds__(256) void gemm_pre_k(
    const float* __restrict__ hb, const float* __restrict__ ha,
    const float* __restrict__ hh, const float* __restrict__ wv,
    const float* __restrict__ Wlr, const float* __restrict__ Wc,
    const float* __restrict__ Wx, const float* __restrict__ gt,
    bf16* __restrict__ pre){
    __shared__ float As[64][17];
    __shared__ float Bs[64][17];
    int t = threadIdx.x;
    int n0 = blockIdx.x*64, m0 = blockIdx.y*64;
    int lrow = t >> 2, lq = (t & 3)*4;
    int ty = t >> 4, tx = t & 15;
    float acc[4][4] = {};
    for (int seg=0; seg<4; ++seg){
        const float* Aseg = (seg==0) ? hb : (seg==1) ? ha : (seg==2) ? hh : wv;
        const float* Ap = Aseg + (size_t)(m0+lrow)*H_;
        const float* Bp;
        if      (seg==0) Bp = Wlr + (size_t)(n0+lrow)*512;
        else if (seg==1) Bp = Wlr + (size_t)(n0+lrow)*512 + 256;
        else if (seg==2) Bp = Wc  + (size_t)(n0+lrow)*H_;
        else             Bp = Wx  + (size_t)(n0+lrow)*H_;
        for (int k0=0;k0<H_;k0+=16){
            __syncthreads();
            float4 av = *(const float4*)(Ap + k0 + lq);
            float4 bv = *(const float4*)(Bp + k0 + lq);
            As[lrow][lq]=av.x; As[lrow][lq+1]=av.y; As[lrow][lq+2]=av.z; As[lrow][lq+3]=av.w;
            Bs[lrow][lq]=bv.x; Bs[lrow][lq+1]=bv.y; Bs[lrow][lq+2]=bv.z; Bs[lrow][lq+3]=bv.w;
            __syncthreads();
            #pragma unroll
            for (int kk=0;kk<16;kk++){
                float a[4], b[4];
                #pragma unroll
                for (int i=0;i<4;i++) a[i]=As[ty*4+i][kk];
                #pragma unroll
                for (int j=0;j<4;j++) b[j]=Bs[tx*4+j][kk];
                #pragma unroll
                for (int i=0;i<4;i++)
                    #pragma unroll
                    for (int j=0;j<4;j++) acc[i][j] = fmaf(a[i], b[j], acc[i][j]);
            }
        }
    }
    #pragma unroll
    for (int i=0;i<4;i++){
        int row = m0 + ty*4 + i;
        #pragma unroll
        for (int j=0;j<4;j++){
            int col = n0 + tx*4 + j;
            pre[(size_t)row*NB + col] = (bf16)(acc[i][j] + gt[(size_t)(row>>9)*NB + col]);
        }
    }
}

// ---------- joint softmax over 5H + state update ----------
__global__ void gates_k(const bf16* __restrict__ pre, const float* __restrict__ cs_in,
                        const float* __restrict__ cb, const float* __restrict__ ca,
                        const float* __restrict__ scs_in,
                        float* __restrict__ hh_out, float* __restrict__ cs_out){
    int m = blockIdx.x, h = threadIdx.x, b = m >> 9;
    __shared__ float r[256];
    const bf16* row = pre + (size_t)m*NB;
    float pg[7];
    #pragma unroll
    for (int g=0; g<7; ++g) pg[g] = (float)row[g*H_ + h];
    float ex[5]; float loc = 0.f;
    #pragma unroll
    for (int g=0; g<5; ++g){ ex[g] = expf(sigm(pg[g])); loc += ex[g]; }
    r[h] = loc; __syncthreads();
    for (int off=128; off; off>>=1){ if (h<off) r[h] += r[h+off]; __syncthreads(); }
    float inv = 1.f / r[0];
    size_t i = (size_t)m*H_ + h;
    // gate order i,l,r,f,s: new_cs = l*cb + f*cs + r*ca + s*scs + i*u
    float nc = ex[1]*inv*cb[i] + ex[3]*inv*cs_in[i] + ex[2]*inv*ca[i]
             + ex[4]*inv*scs_in[b*H_+h] + ex[0]*inv*tanhf(pg[6]);
    cs_out[i] = nc;
    hh_out[i] = sigm(pg[5]) * tanhf(nc);
}

// ---------- output head (float32 out!) ----------
__global__ void head_k(const float* __restrict__ avgh, const float* __restrict__ sv,
                       const float* __restrict__ W1, const float* __restrict__ b1,
                       const float* __restrict__ Wout, const float* __restrict__ bout,
                       float* __restrict__ out){
    int b = blockIdx.x, t = threadIdx.x;
    __shared__ float conc[H_];
    __shared__ float fc[8];
    const float* wr = W1 + (size_t)t*512;
    float d = b1[t];
    for (int k=0;k<H_;k++) d += avgh[b*H_+k]*wr[k];
    for (int k=0;k<H_;k++) d += sv[b*H_+k]*wr[256+k];
    conc[t] = d;
    __syncthreads();
    if (t < C_){
        const float* wo = Wout + (size_t)t*H_;
        float s = bout[t];
        for (int i=0;i<H_;i++) s += conc[i]*wo[i];
        fc[t] = s;
    }
    __syncthreads();
    if (t == 0){
        float mx = fc[0];
        for (int c=1;c<C_;c++) mx = fmaxf(mx, fc[c]);
        float se = 0.f;
        for (int c=0;c<C_;c++) se += expf(fc[c]-mx);
        float lse = mx + logf(se);
        for (int c=0;c<C_;c++) out[b*C_+c] = fc[c]-lse;
    }
    out[B_*C_ + b*H_ + t] = sv[b*H_+t];
}

// ---------------- host ----------------
extern "C" void kernel_launch(void* const* d_in, const int* in_sizes, int n_in,
                              void* d_out, int out_size, void* d_ws, size_t ws_size,
                              hipStream_t stream){
    const int*   idx    = (const int*)d_in[0];
    const float* hh0    = (const float*)d_in[2];
    const float* cs0    = (const float*)d_in[3];
    const float* embed  = (const float*)d_in[4];
    const float* Wlr    = (const float*)d_in[5];
    const float* Wc     = (const float*)d_in[6];
    const float* Wx     = (const float*)d_in[7];
    const float* Wg     = (const float*)d_in[8];
    const float* gbias  = (const float*)d_in[9];
    const float* Wfg_g  = (const float*)d_in[10];
    const float* Wfg_h  = (const float*)d_in[11];
    const float* Wfgi_g = (const float*)d_in[12];
    const float* Wfgi_h = (const float*)d_in[13];
    const float* Wog_g  = (const float*)d_in[14];
    const float* Wog_h  = (const float*)d_in[15];
    const float* b_fg   = (const float*)d_in[16];
    const float* b_fgi  = (const float*)d_in[17];
    const float* W1     = (const float*)d_in[18];
    const float* b1     = (const float*)d_in[19];
    const float* Wout   = (const float*)d_in[20];
    const float* bout   = (const float*)d_in[21];

    uint8_t* p = (uint8_t*)d_ws;
    auto alloc = [&](size_t bytes)->void*{ void* r=(void*)p; p += (bytes + 255) & ~(size_t)255; return r; };
    float* wv   = (float*)alloc((size_t)M_*H_*4);
    float* hb   = (float*)alloc((size_t)M_*H_*4);
    float* ha   = (float*)alloc((size_t)M_*H_*4);
    float* cb   = (float*)alloc((size_t)M_*H_*4);
    float* ca   = (float*)alloc((size_t)M_*H_*4);
    uint8_t* arena = (uint8_t*)alloc((size_t)M_*NB*2);   // pre overlays fgih(f32)+tmp(f32)
    bf16*  pre  = (bf16*)arena;
    float* fgih = (float*)arena;                          // 16.8 MB
    float* tmp  = (float*)(arena + (size_t)M_*H_*4);      // 33.6 MB (total 50.4 <= 58.7)
    float* hhA = (float*)alloc((size_t)M_*H_*4);
    float* csA = (float*)alloc((size_t)M_*H_*4);
    float* hhB = (float*)alloc((size_t)M_*H_*4);
    float* csB = (float*)alloc((size_t)M_*H_*4);
    float* avgh = (float*)alloc(B_*H_*4);
    float* fhg  = (float*)alloc(B_*H_*4);
    float* ogg  = (float*)alloc(B_*H_*4);
    float* svg  = (float*)alloc(B_*H_*4);
    float* scsum= (float*)alloc(B_*H_*4);
    float* svP0 = (float*)alloc(B_*H_*4);
    float* svP1 = (float*)alloc(B_*H_*4);
    float* scP0 = (float*)alloc(B_*H_*4);
    float* scP1 = (float*)alloc(B_*H_*4);
    float* gt   = (float*)alloc((size_t)B_*NB*4);

    gather_k<<<(M_*H_)/256, 256, 0, stream>>>(idx, embed, wv);
    mean_k  <<<B_, 256, 0, stream>>>(hh0, svP0);
    mean_k  <<<B_, 256, 0, stream>>>(cs0, scP0);

    const float *hin = hh0, *cin = cs0;
    float *hout = hhA, *cout = csA;
    float *svin = svP0, *scin = scP0, *svout = svP1, *scout = scP1;

    for (int l=0; l<2; ++l){
        shift2_k<<<M_, 256, 0, stream>>>(hin, hb, ha);
        shift2_k<<<M_, 256, 0, stream>>>(cin, cb, ca);
        mean_k  <<<B_, 256, 0, stream>>>(hin, avgh);
        small_k <<<B_, 256, 0, stream>>>(svin, avgh, Wfg_g, Wfg_h, Wog_g, Wog_h,
                                         Wfgi_g, b_fg, gbias, b_fgi, fhg, ogg, svg);
        gemm_nt_k<<<dim3(4,256), 256, 0, stream>>>(hin, Wfgi_h, fgih);
        score_k <<<M_, 256, 0, stream>>>(fgih, svg, cin, tmp);
        sumS_k  <<<B_, 256, 0, stream>>>(tmp, scsum);
        newscs_k<<<B_, 256, 0, stream>>>(fhg, ogg, scin, scsum, scout, svout);
        gterm_k <<<dim3(7,B_), 256, 0, stream>>>(svout, Wg, gbias, gt);
        gemm_pre_k<<<dim3(28,256), 256, 0, stream>>>(hb, ha, hin, wv, Wlr, Wc, Wx, gt, pre);
        gates_k <<<M_, 256, 0, stream>>>(pre, cin, cb, ca, scin, hout, cout);
        hin = hout; cin = cout;
        hout = (l==0) ? hhB : hhA;
        cout = (l==0) ? csB : csA;
        float* q;
        q = svin; svin = svout; svout = q;
        q = scin; scin = scout; scout = q;
    }
    mean_k<<<B_, 256, 0, stream>>>(hin, avgh);
    head_k<<<B_, 256, 0, stream>>>(avgh, svin, W1, b1, Wout, bout, (float*)d_out);
}

// Round 6
// 722.085 us; speedup vs baseline: 4.0793x; 4.0793x over previous
//
#include <hip/hip_runtime.h>
#include <stdint.h>
#include <math.h>

#define B_   32
#define S_   512
#define H_   256
#define M_   (B_*S_)     // 16384 tokens
#define KBIG 1024        // [hb|ha|hh|wv]
#define NB   1792        // 7*H
#define C_   5

typedef __bf16 bf16;
typedef __bf16 bf16x8 __attribute__((ext_vector_type(8)));
typedef float  floatx4 __attribute__((ext_vector_type(4)));

__device__ __forceinline__ float sigm(float x){ return 1.f/(1.f+expf(-x)); }

// ---------- WT[n=g*256+h][k] = [W_lr[g,h,0:512] | W_c[g,h,:] | W_x[g,h,:]] (f32->bf16) ----------
__global__ void wcomb_k(const float* __restrict__ Wlr, const float* __restrict__ Wc,
                        const float* __restrict__ Wx, bf16* __restrict__ WT){
    int n = blockIdx.x;           // 0..1791
    int g = n >> 8, h = n & 255;
    int k4 = threadIdx.x * 4;     // 0..1020
    const float* src;
    if (k4 < 512)      src = Wlr + ((size_t)(g*256 + h))*512 + k4;
    else if (k4 < 768) src = Wc  + ((size_t)(g*256 + h))*256 + (k4 - 512);
    else               src = Wx  + ((size_t)(g*256 + h))*256 + (k4 - 768);
    float4 v = *(const float4*)src;
    bf16 o[4] = {(bf16)v.x,(bf16)v.y,(bf16)v.z,(bf16)v.w};
    *(uint2*)&WT[(size_t)n*KBIG + k4] = *(uint2*)o;
}

// ---------- generic f32 -> bf16 (n multiple of 1024) ----------
__global__ void cvtw_k(const float* __restrict__ a, bf16* __restrict__ o){
    int i4 = (blockIdx.x*256 + threadIdx.x)*4;
    float4 v = *(const float4*)(a + i4);
    bf16 t[4] = {(bf16)v.x,(bf16)v.y,(bf16)v.z,(bf16)v.w};
    *(uint2*)(o + i4) = *(uint2*)t;
}

// ---------- wv[m,h] = (bf16)embed[idx[m],h] ----------
__global__ void gather_k(const int* __restrict__ idx, const float* __restrict__ embed,
                         bf16* __restrict__ wv){
    int i4 = (blockIdx.x*256 + threadIdx.x)*4;
    int m = i4 >> 8, h = i4 & 255;
    float4 v = *(const float4*)(embed + (size_t)idx[m]*H_ + h);
    bf16 o[4] = {(bf16)v.x,(bf16)v.y,(bf16)v.z,(bf16)v.w};
    *(uint2*)(wv + (size_t)m*H_ + h) = *(uint2*)o;
}

// ---------- out[b,h] = mean_s x[b,s,h] ----------
__global__ void mean_k(const float* __restrict__ x, float* __restrict__ out){
    int b = blockIdx.x, h = threadIdx.x;
    float s = 0.f;
    for (int t=0;t<S_;t++) s += x[((size_t)b*S_ + t)*H_ + h];
    out[b*H_ + h] = s * (1.f/512.f);
}

// ---------- X[m] = [hb | ha | hh | wv] (bf16) ----------
__global__ void buildx_k(const float* __restrict__ hh, const bf16* __restrict__ wv,
                         bf16* __restrict__ X){
    int m = blockIdx.x, h = threadIdx.x;
    int s = m & (S_-1);
    size_t base = (size_t)m*H_ + h;
    float hb = (s>=1    ? hh[base - H_] : 0.f) + (s>=2    ? hh[base - 2*H_] : 0.f);
    float ha = (s<=S_-2 ? hh[base + H_] : 0.f) + (s<=S_-3 ? hh[base + 2*H_] : 0.f);
    bf16* xr = X + (size_t)m*KBIG;
    xr[h]     = (bf16)hb;
    xr[256+h] = (bf16)ha;
    xr[512+h] = (bf16)hh[base];
    xr[768+h] = wv[base];
}

// ---------- small gates ----------
__global__ void small_k(const float* __restrict__ sv, const float* __restrict__ avgh,
    const float* __restrict__ Wfg_g, const float* __restrict__ Wfg_h,
    const float* __restrict__ Wog_g, const float* __restrict__ Wog_h,
    const float* __restrict__ Wfgi_g, const float* __restrict__ b_fg,
    const float* __restrict__ gate_bias, const float* __restrict__ b_fgi,
    float* __restrict__ fhg, float* __restrict__ ogg, float* __restrict__ svg){
    int b = blockIdx.x, h = threadIdx.x;
    __shared__ float ssv[H_], sav[H_];
    ssv[h] = sv[b*H_+h]; sav[h] = avgh[b*H_+h];
    __syncthreads();
    float d1=0,d2=0,d3=0,d4=0,d5=0;
    const float* r1 = Wfg_g  + (size_t)h*H_;
    const float* r2 = Wfg_h  + (size_t)h*H_;
    const float* r3 = Wog_g  + (size_t)h*H_;
    const float* r4 = Wog_h  + (size_t)h*H_;
    const float* r5 = Wfgi_g + (size_t)h*H_;
    for (int k=0;k<H_;k++){
        float a = ssv[k], c = sav[k];
        d1 += a*r1[k]; d2 += c*r2[k]; d3 += a*r3[k]; d4 += c*r4[k]; d5 += a*r5[k];
    }
    fhg[b*H_+h] = sigm(d1 + d2 + b_fg[h]);
    ogg[b*H_+h] = sigm(d3 + d4 + gate_bias[5*H_+h]);   // reference uses gate_bias[5] here
    svg[b*H_+h] = d5 + b_fgi[h];
}

// ---------- MFMA GEMM: C[M,N](bf16) = A[M,K](bf16) @ BT[N,K]^T (+gt epilogue) ----------
template<int EPI>
__global__ __launch_bounds__(256)
void mgemm_k(const bf16* __restrict__ A, const bf16* __restrict__ BT,
             bf16* __restrict__ C, const float* __restrict__ gt,
             int Kdim, int lda, int ldb, int ldc){
    __shared__ alignas(16) bf16 lsA[128*32];
    __shared__ alignas(16) bf16 lsB[128*32];
    int tid  = threadIdx.x;
    int m0 = blockIdx.y * 128, n0 = blockIdx.x * 128;
    int wave = tid >> 6, lane = tid & 63;
    int wm = (wave & 1) * 64, wn = (wave >> 1) * 64;
    int lrow = lane & 15, quad = lane >> 4;

    floatx4 zero = {0.f,0.f,0.f,0.f};
    floatx4 acc[4][4];
    #pragma unroll
    for (int i=0;i<4;i++)
        #pragma unroll
        for (int j=0;j<4;j++) acc[i][j] = zero;

    int srow = tid >> 2;            // 0..63
    int scol = (tid & 3) * 8;       // 0,8,16,24
    const bf16* Abase = A  + (size_t)(m0 + srow)*lda + scol;
    const bf16* Bbase = BT + (size_t)(n0 + srow)*ldb + scol;

    for (int k0 = 0; k0 < Kdim; k0 += 32){
        __syncthreads();
        *(uint4*)&lsA[srow*32 + scol]      = *(const uint4*)(Abase + k0);
        *(uint4*)&lsA[(64+srow)*32 + scol] = *(const uint4*)(Abase + (size_t)64*lda + k0);
        *(uint4*)&lsB[srow*32 + scol]      = *(const uint4*)(Bbase + k0);
        *(uint4*)&lsB[(64+srow)*32 + scol] = *(const uint4*)(Bbase + (size_t)64*ldb + k0);
        __syncthreads();
        bf16x8 af[4], bfr[4];
        #pragma unroll
        for (int mi=0;mi<4;mi++) af[mi]  = *(const bf16x8*)&lsA[(wm+mi*16+lrow)*32 + quad*8];
        #pragma unroll
        for (int ni=0;ni<4;ni++) bfr[ni] = *(const bf16x8*)&lsB[(wn+ni*16+lrow)*32 + quad*8];
        #pragma unroll
        for (int mi=0;mi<4;mi++)
            #pragma unroll
            for (int ni=0;ni<4;ni++)
                acc[mi][ni] = __builtin_amdgcn_mfma_f32_16x16x32_bf16(af[mi], bfr[ni], acc[mi][ni], 0, 0, 0);
    }

    #pragma unroll
    for (int mi=0;mi<4;mi++)
        #pragma unroll
        for (int ni=0;ni<4;ni++){
            int row = m0 + wm + mi*16 + quad*4;     // C/D: row = quad*4 + r
            int col = n0 + wn + ni*16 + lrow;       //      col = lane&15
            #pragma unroll
            for (int r=0;r<4;r++){
                float v = acc[mi][ni][r];
                if (EPI) v += gt[(size_t)((row+r)>>9)*NB + col];
                C[(size_t)(row+r)*ldc + col] = (bf16)v;
            }
        }
}

// ---------- tmp[m,h] = softmax_h(sigmoid(svg + fgih)) * cs[m,h] ----------
__global__ void score_k(const bf16* __restrict__ fgih, const float* __restrict__ svg,
                        const float* __restrict__ cs, float* __restrict__ tmp){
    int m = blockIdx.x, h = threadIdx.x, b = m >> 9;
    __shared__ float r[256];
    float v = sigm(svg[b*H_+h] + (float)fgih[(size_t)m*H_ + h]);
    float e = expf(v);
    r[h] = e; __syncthreads();
    for (int off=128; off; off>>=1){ if (h<off) r[h] += r[h+off]; __syncthreads(); }
    tmp[(size_t)m*H_ + h] = (e / r[0]) * cs[(size_t)m*H_ + h];
}

// ---------- scsum[b,h] = sum_s tmp[b,s,h] ----------
__global__ void sumS_k(const float* __restrict__ tmp, float* __restrict__ scsum){
    int b = blockIdx.x, h = threadIdx.x;
    float s = 0.f;
    for (int t=0;t<S_;t++) s += tmp[((size_t)b*S_ + t)*H_ + h];
    scsum[b*H_+h] = s;
}

// ---------- new_scs / new_sv ----------
__global__ void newscs_k(const float* __restrict__ fhg, const float* __restrict__ ogg,
                         const float* __restrict__ scs_in, const float* __restrict__ scsum,
                         float* __restrict__ scs_out, float* __restrict__ sv_out){
    int b = blockIdx.x, h = threadIdx.x;
    __shared__ float r[256];
    float e = expf(fhg[b*H_+h]);
    r[h] = e; __syncthreads();
    for (int off=128; off; off>>=1){ if (h<off) r[h] += r[h+off]; __syncthreads(); }
    float ns = (e / r[0]) * scs_in[b*H_+h] + scsum[b*H_+h];
    scs_out[b*H_+h] = ns;
    sv_out[b*H_+h]  = ogg[b*H_+h] * tanhf(ns);
}

// ---------- gt[b, g*256+h] = sum_k new_sv[b,k]*W_g[g,h,k] + gate_bias[g,h] ----------
__global__ void gterm_k(const float* __restrict__ svn, const float* __restrict__ Wg,
                        const float* __restrict__ gbias, float* __restrict__ gt){
    int g = blockIdx.x, b = blockIdx.y, h = threadIdx.x;
    __shared__ float s[H_];
    s[h] = svn[b*H_+h]; __syncthreads();
    const float* w = Wg + ((size_t)g*H_ + h)*H_;
    float d = 0.f;
    for (int k=0;k<H_;k++) d += s[k]*w[k];
    gt[(size_t)b*NB + g*H_ + h] = d + gbias[g*H_+h];
}

// ---------- joint softmax over 5H + state update (cb/ca computed inline) ----------
__global__ void gates_k(const bf16* __restrict__ pre, const float* __restrict__ cs_in,
                        const float* __restrict__ scs_in,
                        float* __restrict__ hh_out, float* __restrict__ cs_out){
    int m = blockIdx.x, h = threadIdx.x, b = m >> 9, s = m & (S_-1);
    __shared__ float r[256];
    const bf16* row = pre + (size_t)m*NB;
    float pg[7];
    #pragma unroll
    for (int g=0; g<7; ++g) pg[g] = (float)row[g*H_ + h];
    float ex[5]; float loc = 0.f;
    #pragma unroll
    for (int g=0; g<5; ++g){ ex[g] = expf(sigm(pg[g])); loc += ex[g]; }
    r[h] = loc; __syncthreads();
    for (int off=128; off; off>>=1){ if (h<off) r[h] += r[h+off]; __syncthreads(); }
    float inv = 1.f / r[0];
    size_t i = (size_t)m*H_ + h;
    float cb = (s>=1    ? cs_in[i - H_] : 0.f) + (s>=2    ? cs_in[i - 2*H_] : 0.f);
    float ca = (s<=S_-2 ? cs_in[i + H_] : 0.f) + (s<=S_-3 ? cs_in[i + 2*H_] : 0.f);
    // gate order i,l,r,f,s: new_cs = l*cb + f*cs + r*ca + s*scs + i*u
    float nc = ex[1]*inv*cb + ex[3]*inv*cs_in[i] + ex[2]*inv*ca
             + ex[4]*inv*scs_in[b*H_+h] + ex[0]*inv*tanhf(pg[6]);
    cs_out[i] = nc;
    hh_out[i] = sigm(pg[5]) * tanhf(nc);
}

// ---------- output head (float32 out) ----------
__global__ void head_k(const float* __restrict__ avgh, const float* __restrict__ sv,
                       const float* __restrict__ W1, const float* __restrict__ b1,
                       const float* __restrict__ Wout, const float* __restrict__ bout,
                       float* __restrict__ out){
    int b = blockIdx.x, t = threadIdx.x;
    __shared__ float conc[H_];
    __shared__ float fc[8];
    const float* wr = W1 + (size_t)t*512;
    float d = b1[t];
    for (int k=0;k<H_;k++) d += avgh[b*H_+k]*wr[k];
    for (int k=0;k<H_;k++) d += sv[b*H_+k]*wr[256+k];
    conc[t] = d;
    __syncthreads();
    if (t < C_){
        const float* wo = Wout + (size_t)t*H_;
        float s = bout[t];
        for (int i=0;i<H_;i++) s += conc[i]*wo[i];
        fc[t] = s;
    }
    __syncthreads();
    if (t == 0){
        float mx = fc[0];
        for (int c=1;c<C_;c++) mx = fmaxf(mx, fc[c]);
        float se = 0.f;
        for (int c=0;c<C_;c++) se += expf(fc[c]-mx);
        float lse = mx + logf(se);
        for (int c=0;c<C_;c++) out[b*C_+c] = fc[c]-lse;
    }
    out[B_*C_ + b*H_ + t] = sv[b*H_+t];
}

// ---------------- host ----------------
extern "C" void kernel_launch(void* const* d_in, const int* in_sizes, int n_in,
                              void* d_out, int out_size, void* d_ws, size_t ws_size,
                              hipStream_t stream){
    const int*   idx    = (const int*)d_in[0];
    const float* hh0    = (const float*)d_in[2];
    const float* cs0    = (const float*)d_in[3];
    const float* embed  = (const float*)d_in[4];
    const float* Wlr    = (const float*)d_in[5];
    const float* Wc     = (const float*)d_in[6];
    const float* Wx     = (const float*)d_in[7];
    const float* Wg     = (const float*)d_in[8];
    const float* gbias  = (const float*)d_in[9];
    const float* Wfg_g  = (const float*)d_in[10];
    const float* Wfg_h  = (const float*)d_in[11];
    const float* Wfgi_g = (const float*)d_in[12];
    const float* Wfgi_h = (const float*)d_in[13];
    const float* Wog_g  = (const float*)d_in[14];
    const float* Wog_h  = (const float*)d_in[15];
    const float* b_fg   = (const float*)d_in[16];
    const float* b_fgi  = (const float*)d_in[17];
    const float* W1     = (const float*)d_in[18];
    const float* b1     = (const float*)d_in[19];
    const float* Wout   = (const float*)d_in[20];
    const float* bout   = (const float*)d_in[21];

    uint8_t* p = (uint8_t*)d_ws;
    auto alloc = [&](size_t bytes)->void*{ void* r=(void*)p; p += (bytes + 255) & ~(size_t)255; return r; };
    bf16*  WT    = (bf16*)alloc((size_t)NB*KBIG*2);    //  3.7 MB
    bf16*  WfgiT = (bf16*)alloc((size_t)H_*H_*2);      //  0.13 MB
    bf16*  X     = (bf16*)alloc((size_t)M_*KBIG*2);    // 33.6 MB
    bf16*  wv    = (bf16*)alloc((size_t)M_*H_*2);      //  8.4 MB
    bf16*  pre   = (bf16*)alloc((size_t)M_*NB*2);      // 58.7 MB
    bf16*  fgih  = (bf16*)alloc((size_t)M_*H_*2);      //  8.4 MB
    float* tmp   = (float*)alloc((size_t)M_*H_*4);     // 16.8 MB
    float* hhA = (float*)alloc((size_t)M_*H_*4);
    float* csA = (float*)alloc((size_t)M_*H_*4);
    float* hhB = (float*)alloc((size_t)M_*H_*4);
    float* csB = (float*)alloc((size_t)M_*H_*4);
    float* avgh = (float*)alloc(B_*H_*4);
    float* fhg  = (float*)alloc(B_*H_*4);
    float* ogg  = (float*)alloc(B_*H_*4);
    float* svg  = (float*)alloc(B_*H_*4);
    float* scsum= (float*)alloc(B_*H_*4);
    float* svP0 = (float*)alloc(B_*H_*4);
    float* svP1 = (float*)alloc(B_*H_*4);
    float* scP0 = (float*)alloc(B_*H_*4);
    float* scP1 = (float*)alloc(B_*H_*4);
    float* gt   = (float*)alloc((size_t)B_*NB*4);

    wcomb_k <<<NB,          256, 0, stream>>>(Wlr, Wc, Wx, WT);
    cvtw_k  <<<(H_*H_)/1024,256, 0, stream>>>(Wfgi_h, WfgiT);
    gather_k<<<(M_*H_)/1024,256, 0, stream>>>(idx, embed, wv);
    mean_k  <<<B_,          256, 0, stream>>>(hh0, svP0);
    mean_k  <<<B_,          256, 0, stream>>>(cs0, scP0);

    const float *hin = hh0, *cin = cs0;
    float *hout = hhA, *cout = csA;
    float *svin = svP0, *scin = scP0, *svout = svP1, *scout = scP1;

    for (int l=0; l<2; ++l){
        mean_k  <<<B_, 256, 0, stream>>>(hin, avgh);
        small_k <<<B_, 256, 0, stream>>>(svin, avgh, Wfg_g, Wfg_h, Wog_g, Wog_h,
                                         Wfgi_g, b_fg, gbias, b_fgi, fhg, ogg, svg);
        buildx_k<<<M_, 256, 0, stream>>>(hin, wv, X);
        mgemm_k<0><<<dim3(2,128), 256, 0, stream>>>(X+512, WfgiT, fgih, nullptr,
                                                    H_, KBIG, H_, H_);
        score_k <<<M_, 256, 0, stream>>>(fgih, svg, cin, tmp);
        sumS_k  <<<B_, 256, 0, stream>>>(tmp, scsum);
        newscs_k<<<B_, 256, 0, stream>>>(fhg, ogg, scin, scsum, scout, svout);
        gterm_k <<<dim3(7,B_), 256, 0, stream>>>(svout, Wg, gbias, gt);
        mgemm_k<1><<<dim3(14,128), 256, 0, stream>>>(X, WT, pre, gt,
                                                     KBIG, KBIG, KBIG, NB);
        gates_k <<<M_, 256, 0, stream>>>(pre, cin, scin, hout, cout);
        hin = hout; cin = cout;
        hout = (l==0) ? hhB : hhA;
        cout = (l==0) ? csB : csA;
        float* q;
        q = svin; svin = svout; svout = q;
        q = scin; scin = scout; scout = q;
    }
    mean_k<<<B_, 256, 0, stream>>>(hin, avgh);
    head_k<<<B_, 256, 0, stream>>>(avgh, svin, W1, b1, Wout, bout, (float*)d_out);
}

// Round 7
// 592.771 us; speedup vs baseline: 4.9692x; 1.2182x over previous
//
#include <hip/hip_runtime.h>
#include <stdint.h>
#include <math.h>

#define B_   32
#define S_   512
#define H_   256
#define M_   (B_*S_)     // 16384 tokens
#define KBIG 1024        // [hb|ha|hh|wv]
#define NB   1792        // 7*H
#define C_   5

typedef __bf16 bf16;
typedef __bf16 bf16x8 __attribute__((ext_vector_type(8)));
typedef float  floatx4 __attribute__((ext_vector_type(4)));

__device__ __forceinline__ float sigm(float x){ return 1.f/(1.f+expf(-x)); }

// ---------- WT[n=g*256+h][k] = [W_lr[g,h,0:512] | W_c[g,h,:] | W_x[g,h,:]] (f32->bf16) ----------
__global__ void wcomb_k(const float* __restrict__ Wlr, const float* __restrict__ Wc,
                        const float* __restrict__ Wx, bf16* __restrict__ WT){
    int n = blockIdx.x;           // 0..1791
    int g = n >> 8, h = n & 255;
    int k4 = threadIdx.x * 4;     // 0..1020
    const float* src;
    if (k4 < 512)      src = Wlr + ((size_t)(g*256 + h))*512 + k4;
    else if (k4 < 768) src = Wc  + ((size_t)(g*256 + h))*256 + (k4 - 512);
    else               src = Wx  + ((size_t)(g*256 + h))*256 + (k4 - 768);
    float4 v = *(const float4*)src;
    bf16 o[4] = {(bf16)v.x,(bf16)v.y,(bf16)v.z,(bf16)v.w};
    *(uint2*)&WT[(size_t)n*KBIG + k4] = *(uint2*)o;
}

// ---------- generic f32 -> bf16 (n multiple of 1024) ----------
__global__ void cvtw_k(const float* __restrict__ a, bf16* __restrict__ o){
    int i4 = (blockIdx.x*256 + threadIdx.x)*4;
    float4 v = *(const float4*)(a + i4);
    bf16 t[4] = {(bf16)v.x,(bf16)v.y,(bf16)v.z,(bf16)v.w};
    *(uint2*)(o + i4) = *(uint2*)t;
}

// ---------- wv[m,h] = (bf16)embed[idx[m],h] ----------
__global__ void gather_k(const int* __restrict__ idx, const float* __restrict__ embed,
                         bf16* __restrict__ wv){
    int i4 = (blockIdx.x*256 + threadIdx.x)*4;
    int m = i4 >> 8, h = i4 & 255;
    float4 v = *(const float4*)(embed + (size_t)idx[m]*H_ + h);
    bf16 o[4] = {(bf16)v.x,(bf16)v.y,(bf16)v.z,(bf16)v.w};
    *(uint2*)(wv + (size_t)m*H_ + h) = *(uint2*)o;
}

// ---------- two-stage mean over S ----------
__global__ void mean1_k(const float* __restrict__ x, float* __restrict__ part){
    int b = blockIdx.x, c = blockIdx.y, h = threadIdx.x;   // grid (B_,16)
    const float* p = x + ((size_t)b*S_ + c*32)*H_ + h;
    float s = 0.f;
    #pragma unroll 8
    for (int t=0;t<32;t++) s += p[(size_t)t*H_];
    part[((size_t)b*16 + c)*H_ + h] = s;
}
__global__ void mean2_k(const float* __restrict__ part, float* __restrict__ out){
    int b = blockIdx.x, h = threadIdx.x;
    float s = 0.f;
    #pragma unroll
    for (int c=0;c<16;c++) s += part[((size_t)b*16 + c)*H_ + h];
    out[b*H_ + h] = s * (1.f/512.f);
}

// ---------- X[m] = [hb | ha | hh | wv] (bf16) ----------
__global__ void buildx_k(const float* __restrict__ hh, const bf16* __restrict__ wv,
                         bf16* __restrict__ X){
    int m = blockIdx.x, h = threadIdx.x;
    int s = m & (S_-1);
    size_t base = (size_t)m*H_ + h;
    float hb = (s>=1    ? hh[base - H_] : 0.f) + (s>=2    ? hh[base - 2*H_] : 0.f);
    float ha = (s<=S_-2 ? hh[base + H_] : 0.f) + (s<=S_-3 ? hh[base + 2*H_] : 0.f);
    bf16* xr = X + (size_t)m*KBIG;
    xr[h]     = (bf16)hb;
    xr[256+h] = (bf16)ha;
    xr[512+h] = (bf16)hh[base];
    xr[768+h] = wv[base];
}

// ---------- 5 small matvecs: res[b*5+j][h] ----------
__global__ void mv5_k(const float* __restrict__ sv, const float* __restrict__ avg,
    const float* __restrict__ Wfg_g, const float* __restrict__ Wfg_h,
    const float* __restrict__ Wog_g, const float* __restrict__ Wog_h,
    const float* __restrict__ Wfgi_g, float* __restrict__ res){
    int j = blockIdx.x, b = blockIdx.y, h = threadIdx.x;   // grid (5,B_)
    const float* vec = (j==1 || j==3) ? avg + b*H_ : sv + b*H_;
    const float* W   = (j==0)?Wfg_g:(j==1)?Wfg_h:(j==2)?Wog_g:(j==3)?Wog_h:Wfgi_g;
    __shared__ float v[H_];
    v[h] = vec[h]; __syncthreads();
    const float* w = W + (size_t)h*H_;
    float d = 0.f;
    for (int k=0;k<H_;k++) d += v[k]*w[k];
    res[((size_t)b*5 + j)*H_ + h] = d;
}
__global__ void comb_k(const float* __restrict__ res, const float* __restrict__ b_fg,
                       const float* __restrict__ gbias, const float* __restrict__ b_fgi,
                       float* __restrict__ fhg, float* __restrict__ ogg,
                       float* __restrict__ svg){
    int b = blockIdx.x, h = threadIdx.x;
    const float* r = res + (size_t)b*5*H_;
    fhg[b*H_+h] = sigm(r[h] + r[H_+h] + b_fg[h]);
    ogg[b*H_+h] = sigm(r[2*H_+h] + r[3*H_+h] + gbias[5*H_+h]);  // gate_bias[5] per ref
    svg[b*H_+h] = r[4*H_+h] + b_fgi[h];
}

// ---------- MFMA GEMM: C[M,N](bf16) = A[M,K](bf16) @ BT[N,K]^T (+gt epilogue) ----------
template<int EPI>
__global__ __launch_bounds__(256)
void mgemm_k(const bf16* __restrict__ A, const bf16* __restrict__ BT,
             bf16* __restrict__ C, const float* __restrict__ gt,
             int Kdim, int lda, int ldb, int ldc){
    __shared__ alignas(16) bf16 lsA[128*32];
    __shared__ alignas(16) bf16 lsB[128*32];
    int tid  = threadIdx.x;
    int m0 = blockIdx.y * 128, n0 = blockIdx.x * 128;
    int wave = tid >> 6, lane = tid & 63;
    int wm = (wave & 1) * 64, wn = (wave >> 1) * 64;
    int lrow = lane & 15, quad = lane >> 4;

    floatx4 zero = {0.f,0.f,0.f,0.f};
    floatx4 acc[4][4];
    #pragma unroll
    for (int i=0;i<4;i++)
        #pragma unroll
        for (int j=0;j<4;j++) acc[i][j] = zero;

    int srow = tid >> 2;            // 0..63
    int scol = (tid & 3) * 8;       // 0,8,16,24
    const bf16* Abase = A  + (size_t)(m0 + srow)*lda + scol;
    const bf16* Bbase = BT + (size_t)(n0 + srow)*ldb + scol;

    for (int k0 = 0; k0 < Kdim; k0 += 32){
        __syncthreads();
        *(uint4*)&lsA[srow*32 + scol]      = *(const uint4*)(Abase + k0);
        *(uint4*)&lsA[(64+srow)*32 + scol] = *(const uint4*)(Abase + (size_t)64*lda + k0);
        *(uint4*)&lsB[srow*32 + scol]      = *(const uint4*)(Bbase + k0);
        *(uint4*)&lsB[(64+srow)*32 + scol] = *(const uint4*)(Bbase + (size_t)64*ldb + k0);
        __syncthreads();
        bf16x8 af[4], bfr[4];
        #pragma unroll
        for (int mi=0;mi<4;mi++) af[mi]  = *(const bf16x8*)&lsA[(wm+mi*16+lrow)*32 + quad*8];
        #pragma unroll
        for (int ni=0;ni<4;ni++) bfr[ni] = *(const bf16x8*)&lsB[(wn+ni*16+lrow)*32 + quad*8];
        #pragma unroll
        for (int mi=0;mi<4;mi++)
            #pragma unroll
            for (int ni=0;ni<4;ni++)
                acc[mi][ni] = __builtin_amdgcn_mfma_f32_16x16x32_bf16(af[mi], bfr[ni], acc[mi][ni], 0, 0, 0);
    }

    #pragma unroll
    for (int mi=0;mi<4;mi++)
        #pragma unroll
        for (int ni=0;ni<4;ni++){
            int row = m0 + wm + mi*16 + quad*4;     // C/D: row = quad*4 + r
            int col = n0 + wn + ni*16 + lrow;       //      col = lane&15
            #pragma unroll
            for (int r=0;r<4;r++){
                float v = acc[mi][ni][r];
                if (EPI) v += gt[(size_t)((row+r)>>9)*NB + col];
                C[(size_t)(row+r)*ldc + col] = (bf16)v;
            }
        }
}

// ---------- fused: partial[b,chunk,h] = sum_{16 steps} softmax_h(sigm(svg+fgih))*cs ----------
__global__ void scorep_k(const bf16* __restrict__ fgih, const float* __restrict__ svg,
                         const float* __restrict__ cs, float* __restrict__ part){
    int chunk = blockIdx.x, b = blockIdx.y, h = threadIdx.x;   // grid (32,B_)
    __shared__ float r[256];
    float sw = svg[b*H_+h];
    float acc = 0.f;
    for (int j=0;j<16;j++){
        int m = b*S_ + chunk*16 + j;
        float e = expf(sigm(sw + (float)fgih[(size_t)m*H_ + h]));
        r[h] = e; __syncthreads();
        for (int off=128; off; off>>=1){ if (h<off) r[h] += r[h+off]; __syncthreads(); }
        acc += (e / r[0]) * cs[(size_t)m*H_ + h];
        __syncthreads();
    }
    part[((size_t)b*32 + chunk)*H_ + h] = acc;
}

// ---------- new_scs / new_sv (sums 32 partials) ----------
__global__ void newscs_k(const float* __restrict__ part, const float* __restrict__ fhg,
                         const float* __restrict__ ogg, const float* __restrict__ scs_in,
                         float* __restrict__ scs_out, float* __restrict__ sv_out){
    int b = blockIdx.x, h = threadIdx.x;
    __shared__ float r[256];
    float dot = 0.f;
    #pragma unroll 8
    for (int c=0;c<32;c++) dot += part[((size_t)b*32+c)*H_ + h];
    float e = expf(fhg[b*H_+h]);
    r[h] = e; __syncthreads();
    for (int off=128; off; off>>=1){ if (h<off) r[h] += r[h+off]; __syncthreads(); }
    float ns = (e / r[0]) * scs_in[b*H_+h] + dot;
    scs_out[b*H_+h] = ns;
    sv_out[b*H_+h]  = ogg[b*H_+h] * tanhf(ns);
}

// ---------- gt[b, g*256+h] = sum_k new_sv[b,k]*W_g[g,h,k] + gate_bias[g,h] ----------
__global__ void gterm_k(const float* __restrict__ svn, const float* __restrict__ Wg,
                        const float* __restrict__ gbias, float* __restrict__ gt){
    int g = blockIdx.x, b = blockIdx.y, h = threadIdx.x;
    __shared__ float s[H_];
    s[h] = svn[b*H_+h]; __syncthreads();
    const float* w = Wg + ((size_t)g*H_ + h)*H_;
    float d = 0.f;
    for (int k=0;k<H_;k++) d += s[k]*w[k];
    gt[(size_t)b*NB + g*H_ + h] = d + gbias[g*H_+h];
}

// ---------- joint softmax over 5H + state update (cb/ca inline) ----------
__global__ void gates_k(const bf16* __restrict__ pre, const float* __restrict__ cs_in,
                        const float* __restrict__ scs_in,
                        float* __restrict__ hh_out, float* __restrict__ cs_out){
    int m = blockIdx.x, h = threadIdx.x, b = m >> 9, s = m & (S_-1);
    __shared__ float r[256];
    const bf16* row = pre + (size_t)m*NB;
    float pg[7];
    #pragma unroll
    for (int g=0; g<7; ++g) pg[g] = (float)row[g*H_ + h];
    float ex[5]; float loc = 0.f;
    #pragma unroll
    for (int g=0; g<5; ++g){ ex[g] = expf(sigm(pg[g])); loc += ex[g]; }
    r[h] = loc; __syncthreads();
    for (int off=128; off; off>>=1){ if (h<off) r[h] += r[h+off]; __syncthreads(); }
    float inv = 1.f / r[0];
    size_t i = (size_t)m*H_ + h;
    float cb = (s>=1    ? cs_in[i - H_] : 0.f) + (s>=2    ? cs_in[i - 2*H_] : 0.f);
    float ca = (s<=S_-2 ? cs_in[i + H_] : 0.f) + (s<=S_-3 ? cs_in[i + 2*H_] : 0.f);
    // gate order i,l,r,f,s: new_cs = l*cb + f*cs + r*ca + s*scs + i*u
    float nc = ex[1]*inv*cb + ex[3]*inv*cs_in[i] + ex[2]*inv*ca
             + ex[4]*inv*scs_in[b*H_+h] + ex[0]*inv*tanhf(pg[6]);
    cs_out[i] = nc;
    hh_out[i] = sigm(pg[5]) * tanhf(nc);
}

// ---------- output head (float32 out) ----------
__global__ void head_k(const float* __restrict__ avgh, const float* __restrict__ sv,
                       const float* __restrict__ W1, const float* __restrict__ b1,
                       const float* __restrict__ Wout, const float* __restrict__ bout,
                       float* __restrict__ out){
    int b = blockIdx.x, t = threadIdx.x;
    __shared__ float conc[H_];
    __shared__ float fc[8];
    const float* wr = W1 + (size_t)t*512;
    float d = b1[t];
    for (int k=0;k<H_;k++) d += avgh[b*H_+k]*wr[k];
    for (int k=0;k<H_;k++) d += sv[b*H_+k]*wr[256+k];
    conc[t] = d;
    __syncthreads();
    if (t < C_){
        const float* wo = Wout + (size_t)t*H_;
        float s = bout[t];
        for (int i=0;i<H_;i++) s += conc[i]*wo[i];
        fc[t] = s;
    }
    __syncthreads();
    if (t == 0){
        float mx = fc[0];
        for (int c=1;c<C_;c++) mx = fmaxf(mx, fc[c]);
        float se = 0.f;
        for (int c=0;c<C_;c++) se += expf(fc[c]-mx);
        float lse = mx + logf(se);
        for (int c=0;c<C_;c++) out[b*C_+c] = fc[c]-lse;
    }
    out[B_*C_ + b*H_ + t] = sv[b*H_+t];
}

// ---------------- host ----------------
extern "C" void kernel_launch(void* const* d_in, const int* in_sizes, int n_in,
                              void* d_out, int out_size, void* d_ws, size_t ws_size,
                              hipStream_t stream){
    const int*   idx    = (const int*)d_in[0];
    const float* hh0    = (const float*)d_in[2];
    const float* cs0    = (const float*)d_in[3];
    const float* embed  = (const float*)d_in[4];
    const float* Wlr    = (const float*)d_in[5];
    const float* Wc     = (const float*)d_in[6];
    const float* Wx     = (const float*)d_in[7];
    const float* Wg     = (const float*)d_in[8];
    const float* gbias  = (const float*)d_in[9];
    const float* Wfg_g  = (const float*)d_in[10];
    const float* Wfg_h  = (const float*)d_in[11];
    const float* Wfgi_g = (const float*)d_in[12];
    const float* Wfgi_h = (const float*)d_in[13];
    const float* Wog_g  = (const float*)d_in[14];
    const float* Wog_h  = (const float*)d_in[15];
    const float* b_fg   = (const float*)d_in[16];
    const float* b_fgi  = (const float*)d_in[17];
    const float* W1     = (const float*)d_in[18];
    const float* b1     = (const float*)d_in[19];
    const float* Wout   = (const float*)d_in[20];
    const float* bout   = (const float*)d_in[21];

    uint8_t* p = (uint8_t*)d_ws;
    auto alloc = [&](size_t bytes)->void*{ void* r=(void*)p; p += (bytes + 255) & ~(size_t)255; return r; };
    bf16*  WT    = (bf16*)alloc((size_t)NB*KBIG*2);    //  3.7 MB
    bf16*  WfgiT = (bf16*)alloc((size_t)H_*H_*2);
    bf16*  X     = (bf16*)alloc((size_t)M_*KBIG*2);    // 33.6 MB
    bf16*  wv    = (bf16*)alloc((size_t)M_*H_*2);      //  8.4 MB
    bf16*  pre   = (bf16*)alloc((size_t)M_*NB*2);      // 58.7 MB
    bf16*  fgih  = (bf16*)alloc((size_t)M_*H_*2);      //  8.4 MB
    float* hhA = (float*)alloc((size_t)M_*H_*4);
    float* csA = (float*)alloc((size_t)M_*H_*4);
    float* hhB = (float*)alloc((size_t)M_*H_*4);
    float* csB = (float*)alloc((size_t)M_*H_*4);
    float* mpart= (float*)alloc((size_t)B_*16*H_*4);
    float* part = (float*)alloc((size_t)B_*32*H_*4);
    float* res5 = (float*)alloc((size_t)B_*5*H_*4);
    float* avgh = (float*)alloc(B_*H_*4);
    float* fhg  = (float*)alloc(B_*H_*4);
    float* ogg  = (float*)alloc(B_*H_*4);
    float* svg  = (float*)alloc(B_*H_*4);
    float* svP0 = (float*)alloc(B_*H_*4);
    float* svP1 = (float*)alloc(B_*H_*4);
    float* scP0 = (float*)alloc(B_*H_*4);
    float* scP1 = (float*)alloc(B_*H_*4);
    float* gt   = (float*)alloc((size_t)B_*NB*4);

    wcomb_k <<<NB,          256, 0, stream>>>(Wlr, Wc, Wx, WT);
    cvtw_k  <<<(H_*H_)/1024,256, 0, stream>>>(Wfgi_h, WfgiT);
    gather_k<<<(M_*H_)/1024,256, 0, stream>>>(idx, embed, wv);
    mean1_k <<<dim3(B_,16), 256, 0, stream>>>(hh0, mpart);
    mean2_k <<<B_,          256, 0, stream>>>(mpart, svP0);   // sv0 == avg_hh(layer0)
    mean1_k <<<dim3(B_,16), 256, 0, stream>>>(cs0, mpart);
    mean2_k <<<B_,          256, 0, stream>>>(mpart, scP0);

    const float *hin = hh0, *cin = cs0;
    float *hout = hhA, *cout = csA;
    float *svin = svP0, *scin = scP0, *svout = svP1, *scout = scP1;

    for (int l=0; l<2; ++l){
        const float* avgp;
        if (l == 0){
            avgp = svin;            // mean(hh0) == initial sv
        } else {
            mean1_k<<<dim3(B_,16), 256, 0, stream>>>(hin, mpart);
            mean2_k<<<B_,          256, 0, stream>>>(mpart, avgh);
            avgp = avgh;
        }
        mv5_k   <<<dim3(5,B_), 256, 0, stream>>>(svin, avgp, Wfg_g, Wfg_h, Wog_g,
                                                 Wog_h, Wfgi_g, res5);
        comb_k  <<<B_, 256, 0, stream>>>(res5, b_fg, gbias, b_fgi, fhg, ogg, svg);
        buildx_k<<<M_, 256, 0, stream>>>(hin, wv, X);
        mgemm_k<0><<<dim3(2,128), 256, 0, stream>>>(X+512, WfgiT, fgih, nullptr,
                                                    H_, KBIG, H_, H_);
        scorep_k<<<dim3(32,B_), 256, 0, stream>>>(fgih, svg, cin, part);
        newscs_k<<<B_, 256, 0, stream>>>(part, fhg, ogg, scin, scout, svout);
        gterm_k <<<dim3(7,B_), 256, 0, stream>>>(svout, Wg, gbias, gt);
        mgemm_k<1><<<dim3(14,128), 256, 0, stream>>>(X, WT, pre, gt,
                                                     KBIG, KBIG, KBIG, NB);
        gates_k <<<M_, 256, 0, stream>>>(pre, cin, scin, hout, cout);
        hin = hout; cin = cout;
        hout = (l==0) ? hhB : hhA;
        cout = (l==0) ? csB : csA;
        float* q;
        q = svin; svin = svout; svout = q;
        q = scin; scin = scout; scout = q;
    }
    mean1_k<<<dim3(B_,16), 256, 0, stream>>>(hin, mpart);
    mean2_k<<<B_,          256, 0, stream>>>(mpart, avgh);
    head_k <<<B_, 256, 0, stream>>>(avgh, svin, W1, b1, Wout, bout, (float*)d_out);
}

// Round 8
// 571.774 us; speedup vs baseline: 5.1517x; 1.0367x over previous
//
#include <hip/hip_runtime.h>
#include <stdint.h>
#include <math.h>

#define B_   32
#define S_   512
#define H_   256
#define M_   (B_*S_)     // 16384 tokens
#define KBIG 1024        // [hb|ha|hh|wv]
#define NB   1792        // 7*H
#define C_   5

typedef __bf16 bf16;
typedef __bf16 bf16x8 __attribute__((ext_vector_type(8)));
typedef float  floatx4 __attribute__((ext_vector_type(4)));

__device__ __forceinline__ float sigm(float x){ return 1.f/(1.f+expf(-x)); }

// async global->LDS, 16B per lane; LDS dest must be wave-uniform base + lane*16
__device__ __forceinline__ void gl16(const bf16* g, bf16* l){
    __builtin_amdgcn_global_load_lds(
        (const __attribute__((address_space(1))) unsigned int*)g,
        (__attribute__((address_space(3))) unsigned int*)l, 16, 0, 0);
}

// ---------- WT[n=g*256+h][k] = [W_lr[g,h,0:512] | W_c[g,h,:] | W_x[g,h,:]] (f32->bf16) ----------
__global__ void wcomb_k(const float* __restrict__ Wlr, const float* __restrict__ Wc,
                        const float* __restrict__ Wx, bf16* __restrict__ WT){
    int n = blockIdx.x;           // 0..1791
    int g = n >> 8, h = n & 255;
    int k4 = threadIdx.x * 4;     // 0..1020
    const float* src;
    if (k4 < 512)      src = Wlr + ((size_t)(g*256 + h))*512 + k4;
    else if (k4 < 768) src = Wc  + ((size_t)(g*256 + h))*256 + (k4 - 512);
    else               src = Wx  + ((size_t)(g*256 + h))*256 + (k4 - 768);
    float4 v = *(const float4*)src;
    bf16 o[4] = {(bf16)v.x,(bf16)v.y,(bf16)v.z,(bf16)v.w};
    *(uint2*)&WT[(size_t)n*KBIG + k4] = *(uint2*)o;
}

// ---------- generic f32 -> bf16 (n multiple of 1024) ----------
__global__ void cvtw_k(const float* __restrict__ a, bf16* __restrict__ o){
    int i4 = (blockIdx.x*256 + threadIdx.x)*4;
    float4 v = *(const float4*)(a + i4);
    bf16 t[4] = {(bf16)v.x,(bf16)v.y,(bf16)v.z,(bf16)v.w};
    *(uint2*)(o + i4) = *(uint2*)t;
}

// ---------- wv[m,h] = (bf16)embed[idx[m],h] ----------
__global__ void gather_k(const int* __restrict__ idx, const float* __restrict__ embed,
                         bf16* __restrict__ wv){
    int i4 = (blockIdx.x*256 + threadIdx.x)*4;
    int m = i4 >> 8, h = i4 & 255;
    float4 v = *(const float4*)(embed + (size_t)idx[m]*H_ + h);
    bf16 o[4] = {(bf16)v.x,(bf16)v.y,(bf16)v.z,(bf16)v.w};
    *(uint2*)(wv + (size_t)m*H_ + h) = *(uint2*)o;
}

// ---------- two-stage mean over S ----------
__global__ void mean1_k(const float* __restrict__ x, float* __restrict__ part){
    int b = blockIdx.x, c = blockIdx.y, h = threadIdx.x;   // grid (B_,16)
    const float* p = x + ((size_t)b*S_ + c*32)*H_ + h;
    float s = 0.f;
    #pragma unroll 8
    for (int t=0;t<32;t++) s += p[(size_t)t*H_];
    part[((size_t)b*16 + c)*H_ + h] = s;
}
__global__ void mean2_k(const float* __restrict__ part, float* __restrict__ out){
    int b = blockIdx.x, h = threadIdx.x;
    float s = 0.f;
    #pragma unroll
    for (int c=0;c<16;c++) s += part[((size_t)b*16 + c)*H_ + h];
    out[b*H_ + h] = s * (1.f/512.f);
}

// ---------- X[m] = [hb | ha | hh | wv] (bf16) ----------
__global__ void buildx_k(const float* __restrict__ hh, const bf16* __restrict__ wv,
                         bf16* __restrict__ X){
    int m = blockIdx.x, h = threadIdx.x;
    int s = m & (S_-1);
    size_t base = (size_t)m*H_ + h;
    float hb = (s>=1    ? hh[base - H_] : 0.f) + (s>=2    ? hh[base - 2*H_] : 0.f);
    float ha = (s<=S_-2 ? hh[base + H_] : 0.f) + (s<=S_-3 ? hh[base + 2*H_] : 0.f);
    bf16* xr = X + (size_t)m*KBIG;
    xr[h]     = (bf16)hb;
    xr[256+h] = (bf16)ha;
    xr[512+h] = (bf16)hh[base];
    xr[768+h] = wv[base];
}

// ---------- 5 small matvecs: res[b*5+j][h] ----------
__global__ void mv5_k(const float* __restrict__ sv, const float* __restrict__ avg,
    const float* __restrict__ Wfg_g, const float* __restrict__ Wfg_h,
    const float* __restrict__ Wog_g, const float* __restrict__ Wog_h,
    const float* __restrict__ Wfgi_g, float* __restrict__ res){
    int j = blockIdx.x, b = blockIdx.y, h = threadIdx.x;   // grid (5,B_)
    const float* vec = (j==1 || j==3) ? avg + b*H_ : sv + b*H_;
    const float* W   = (j==0)?Wfg_g:(j==1)?Wfg_h:(j==2)?Wog_g:(j==3)?Wog_h:Wfgi_g;
    __shared__ float v[H_];
    v[h] = vec[h]; __syncthreads();
    const float* w = W + (size_t)h*H_;
    float d = 0.f;
    for (int k=0;k<H_;k++) d += v[k]*w[k];
    res[((size_t)b*5 + j)*H_ + h] = d;
}
__global__ void comb_k(const float* __restrict__ res, const float* __restrict__ b_fg,
                       const float* __restrict__ gbias, const float* __restrict__ b_fgi,
                       float* __restrict__ fhg, float* __restrict__ ogg,
                       float* __restrict__ svg){
    int b = blockIdx.x, h = threadIdx.x;
    const float* r = res + (size_t)b*5*H_;
    fhg[b*H_+h] = sigm(r[h] + r[H_+h] + b_fg[h]);
    ogg[b*H_+h] = sigm(r[2*H_+h] + r[3*H_+h] + gbias[5*H_+h]);  // gate_bias[5] per ref
    svg[b*H_+h] = r[4*H_+h] + b_fgi[h];
}

// ---------- MFMA GEMM with global_load_lds staging ----------
template<int EPI>
__global__ __launch_bounds__(256)
void mgemm_k(const bf16* __restrict__ A, const bf16* __restrict__ BT,
             bf16* __restrict__ C, const float* __restrict__ gt,
             int Kdim, int lda, int ldb, int ldc){
    __shared__ alignas(16) bf16 lsA[128*32];
    __shared__ alignas(16) bf16 lsB[128*32];
    int tid  = threadIdx.x;
    int m0 = blockIdx.y * 128, n0 = blockIdx.x * 128;
    int wave = tid >> 6, lane = tid & 63;
    int wm = (wave & 1) * 64, wn = (wave >> 1) * 64;
    int lrow = lane & 15, quad = lane >> 4;

    floatx4 zero = {0.f,0.f,0.f,0.f};
    floatx4 acc[4][4];
    #pragma unroll
    for (int i=0;i<4;i++)
        #pragma unroll
        for (int j=0;j<4;j++) acc[i][j] = zero;

    int srow = tid >> 2;            // 0..63
    int scol = (tid & 3) * 8;       // 0,8,16,24  -> lds offset = tid*16B (contract OK)
    const bf16* Abase = A  + (size_t)(m0 + srow)*lda + scol;
    const bf16* Bbase = BT + (size_t)(n0 + srow)*ldb + scol;
    bf16* dA0 = &lsA[srow*32 + scol];
    bf16* dA1 = &lsA[(64+srow)*32 + scol];
    bf16* dB0 = &lsB[srow*32 + scol];
    bf16* dB1 = &lsB[(64+srow)*32 + scol];

    for (int k0 = 0; k0 < Kdim; k0 += 32){
        __syncthreads();
        gl16(Abase + k0,                     dA0);
        gl16(Abase + (size_t)64*lda + k0,    dA1);
        gl16(Bbase + k0,                     dB0);
        gl16(Bbase + (size_t)64*ldb + k0,    dB1);
        __syncthreads();
        bf16x8 af[4], bfr[4];
        #pragma unroll
        for (int mi=0;mi<4;mi++) af[mi]  = *(const bf16x8*)&lsA[(wm+mi*16+lrow)*32 + quad*8];
        #pragma unroll
        for (int ni=0;ni<4;ni++) bfr[ni] = *(const bf16x8*)&lsB[(wn+ni*16+lrow)*32 + quad*8];
        #pragma unroll
        for (int mi=0;mi<4;mi++)
            #pragma unroll
            for (int ni=0;ni<4;ni++)
                acc[mi][ni] = __builtin_amdgcn_mfma_f32_16x16x32_bf16(af[mi], bfr[ni], acc[mi][ni], 0, 0, 0);
    }

    #pragma unroll
    for (int mi=0;mi<4;mi++)
        #pragma unroll
        for (int ni=0;ni<4;ni++){
            int row = m0 + wm + mi*16 + quad*4;     // C/D: row = quad*4 + r
            int col = n0 + wn + ni*16 + lrow;       //      col = lane&15
            #pragma unroll
            for (int r=0;r<4;r++){
                float v = acc[mi][ni][r];
                if (EPI) v += gt[(size_t)((row+r)>>9)*NB + col];
                C[(size_t)(row+r)*ldc + col] = (bf16)v;
            }
        }
}

// ---------- fused score+partial: wave per token, shuffle softmax ----------
__global__ void scorep_k(const bf16* __restrict__ fgih, const float* __restrict__ svg,
                         const float* __restrict__ cs, float* __restrict__ part){
    int chunk = blockIdx.x, b = blockIdx.y;                 // grid (32,B_)
    int tid = threadIdx.x, wave = tid >> 6, lane = tid & 63;
    __shared__ float acc4[4][256];
    float sw[4], acc[4] = {0.f,0.f,0.f,0.f};
    #pragma unroll
    for (int j=0;j<4;j++) sw[j] = svg[b*H_ + lane + 64*j];
    for (int t=wave; t<16; t+=4){
        int m = b*S_ + chunk*16 + t;
        const bf16* fr = fgih + (size_t)m*H_;
        float e[4], loc = 0.f;
        #pragma unroll
        for (int j=0;j<4;j++){ e[j] = expf(sigm(sw[j] + (float)fr[lane+64*j])); loc += e[j]; }
        #pragma unroll
        for (int off=32; off; off>>=1) loc += __shfl_xor(loc, off, 64);
        float inv = 1.f/loc;
        const float* cr = cs + (size_t)m*H_;
        #pragma unroll
        for (int j=0;j<4;j++) acc[j] += e[j]*inv*cr[lane+64*j];
    }
    #pragma unroll
    for (int j=0;j<4;j++) acc4[wave][lane+64*j] = acc[j];
    __syncthreads();
    part[((size_t)b*32 + chunk)*H_ + tid] =
        acc4[0][tid] + acc4[1][tid] + acc4[2][tid] + acc4[3][tid];
}

// ---------- new_scs / new_sv (sums 32 partials) ----------
__global__ void newscs_k(const float* __restrict__ part, const float* __restrict__ fhg,
                         const float* __restrict__ ogg, const float* __restrict__ scs_in,
                         float* __restrict__ scs_out, float* __restrict__ sv_out){
    int b = blockIdx.x, h = threadIdx.x;
    __shared__ float r[256];
    float dot = 0.f;
    #pragma unroll 8
    for (int c=0;c<32;c++) dot += part[((size_t)b*32+c)*H_ + h];
    float e = expf(fhg[b*H_+h]);
    r[h] = e; __syncthreads();
    for (int off=128; off; off>>=1){ if (h<off) r[h] += r[h+off]; __syncthreads(); }
    float ns = (e / r[0]) * scs_in[b*H_+h] + dot;
    scs_out[b*H_+h] = ns;
    sv_out[b*H_+h]  = ogg[b*H_+h] * tanhf(ns);
}

// ---------- gt[b, g*256+h] = sum_k new_sv[b,k]*W_g[g,h,k] + gate_bias[g,h] ----------
__global__ void gterm_k(const float* __restrict__ svn, const float* __restrict__ Wg,
                        const float* __restrict__ gbias, float* __restrict__ gt){
    int g = blockIdx.x, b = blockIdx.y, h = threadIdx.x;
    __shared__ float s[H_];
    s[h] = svn[b*H_+h]; __syncthreads();
    const float* w = Wg + ((size_t)g*H_ + h)*H_;
    float d = 0.f;
    for (int k=0;k<H_;k++) d += s[k]*w[k];
    gt[(size_t)b*NB + g*H_ + h] = d + gbias[g*H_+h];
}

// ---------- joint softmax over 5H + state update: wave per token, shuffle reduce ----------
__global__ void gates_k(const bf16* __restrict__ pre, const float* __restrict__ cs_in,
                        const float* __restrict__ scs_in,
                        float* __restrict__ hh_out, float* __restrict__ cs_out){
    int tid = threadIdx.x, wave = tid >> 6, lane = tid & 63;
    int m = blockIdx.x*4 + wave;                             // grid M_/4
    int b = m >> 9, s = m & (S_-1);
    const bf16* row = pre + (size_t)m*NB;
    float ex[4][5], og[4], u[4];
    float loc = 0.f;
    #pragma unroll
    for (int j=0;j<4;j++){
        int h = lane + 64*j;
        #pragma unroll
        for (int g=0; g<5; ++g){
            float e = expf(sigm((float)row[g*H_ + h]));
            ex[j][g] = e; loc += e;
        }
        og[j] = sigm((float)row[5*H_ + h]);
        u[j]  = tanhf((float)row[6*H_ + h]);
    }
    #pragma unroll
    for (int off=32; off; off>>=1) loc += __shfl_xor(loc, off, 64);
    float inv = 1.f / loc;
    #pragma unroll
    for (int j=0;j<4;j++){
        int h = lane + 64*j;
        size_t i = (size_t)m*H_ + h;
        float cb = (s>=1    ? cs_in[i - H_] : 0.f) + (s>=2    ? cs_in[i - 2*H_] : 0.f);
        float ca = (s<=S_-2 ? cs_in[i + H_] : 0.f) + (s<=S_-3 ? cs_in[i + 2*H_] : 0.f);
        // gate order i,l,r,f,s: new_cs = l*cb + f*cs + r*ca + s*scs + i*u
        float nc = ex[j][1]*inv*cb + ex[j][3]*inv*cs_in[i] + ex[j][2]*inv*ca
                 + ex[j][4]*inv*scs_in[b*H_+h] + ex[j][0]*inv*u[j];
        cs_out[i] = nc;
        hh_out[i] = og[j] * tanhf(nc);
    }
}

// ---------- output head (float32 out) ----------
__global__ void head_k(const float* __restrict__ avgh, const float* __restrict__ sv,
                       const float* __restrict__ W1, const float* __restrict__ b1,
                       const float* __restrict__ Wout, const float* __restrict__ bout,
                       float* __restrict__ out){
    int b = blockIdx.x, t = threadIdx.x;
    __shared__ float conc[H_];
    __shared__ float fc[8];
    const float* wr = W1 + (size_t)t*512;
    float d = b1[t];
    for (int k=0;k<H_;k++) d += avgh[b*H_+k]*wr[k];
    for (int k=0;k<H_;k++) d += sv[b*H_+k]*wr[256+k];
    conc[t] = d;
    __syncthreads();
    if (t < C_){
        const float* wo = Wout + (size_t)t*H_;
        float s = bout[t];
        for (int i=0;i<H_;i++) s += conc[i]*wo[i];
        fc[t] = s;
    }
    __syncthreads();
    if (t == 0){
        float mx = fc[0];
        for (int c=1;c<C_;c++) mx = fmaxf(mx, fc[c]);
        float se = 0.f;
        for (int c=0;c<C_;c++) se += expf(fc[c]-mx);
        float lse = mx + logf(se);
        for (int c=0;c<C_;c++) out[b*C_+c] = fc[c]-lse;
    }
    out[B_*C_ + b*H_ + t] = sv[b*H_+t];
}

// ---------------- host ----------------
extern "C" void kernel_launch(void* const* d_in, const int* in_sizes, int n_in,
                              void* d_out, int out_size, void* d_ws, size_t ws_size,
                              hipStream_t stream){
    const int*   idx    = (const int*)d_in[0];
    const float* hh0    = (const float*)d_in[2];
    const float* cs0    = (const float*)d_in[3];
    const float* embed  = (const float*)d_in[4];
    const float* Wlr    = (const float*)d_in[5];
    const float* Wc     = (const float*)d_in[6];
    const float* Wx     = (const float*)d_in[7];
    const float* Wg     = (const float*)d_in[8];
    const float* gbias  = (const float*)d_in[9];
    const float* Wfg_g  = (const float*)d_in[10];
    const float* Wfg_h  = (const float*)d_in[11];
    const float* Wfgi_g = (const float*)d_in[12];
    const float* Wfgi_h = (const float*)d_in[13];
    const float* Wog_g  = (const float*)d_in[14];
    const float* Wog_h  = (const float*)d_in[15];
    const float* b_fg   = (const float*)d_in[16];
    const float* b_fgi  = (const float*)d_in[17];
    const float* W1     = (const float*)d_in[18];
    const float* b1     = (const float*)d_in[19];
    const float* Wout   = (const float*)d_in[20];
    const float* bout   = (const float*)d_in[21];

    uint8_t* p = (uint8_t*)d_ws;
    auto alloc = [&](size_t bytes)->void*{ void* r=(void*)p; p += (bytes + 255) & ~(size_t)255; return r; };
    bf16*  WT    = (bf16*)alloc((size_t)NB*KBIG*2);    //  3.7 MB
    bf16*  WfgiT = (bf16*)alloc((size_t)H_*H_*2);
    bf16*  X     = (bf16*)alloc((size_t)M_*KBIG*2);    // 33.6 MB
    bf16*  wv    = (bf16*)alloc((size_t)M_*H_*2);      //  8.4 MB
    bf16*  pre   = (bf16*)alloc((size_t)M_*NB*2);      // 58.7 MB
    bf16*  fgih  = (bf16*)alloc((size_t)M_*H_*2);      //  8.4 MB
    float* hhA = (float*)alloc((size_t)M_*H_*4);
    float* csA = (float*)alloc((size_t)M_*H_*4);
    float* hhB = (float*)alloc((size_t)M_*H_*4);
    float* csB = (float*)alloc((size_t)M_*H_*4);
    float* mpart= (float*)alloc((size_t)B_*16*H_*4);
    float* part = (float*)alloc((size_t)B_*32*H_*4);
    float* res5 = (float*)alloc((size_t)B_*5*H_*4);
    float* avgh = (float*)alloc(B_*H_*4);
    float* fhg  = (float*)alloc(B_*H_*4);
    float* ogg  = (float*)alloc(B_*H_*4);
    float* svg  = (float*)alloc(B_*H_*4);
    float* svP0 = (float*)alloc(B_*H_*4);
    float* svP1 = (float*)alloc(B_*H_*4);
    float* scP0 = (float*)alloc(B_*H_*4);
    float* scP1 = (float*)alloc(B_*H_*4);
    float* gt   = (float*)alloc((size_t)B_*NB*4);

    wcomb_k <<<NB,          256, 0, stream>>>(Wlr, Wc, Wx, WT);
    cvtw_k  <<<(H_*H_)/1024,256, 0, stream>>>(Wfgi_h, WfgiT);
    gather_k<<<(M_*H_)/1024,256, 0, stream>>>(idx, embed, wv);
    mean1_k <<<dim3(B_,16), 256, 0, stream>>>(hh0, mpart);
    mean2_k <<<B_,          256, 0, stream>>>(mpart, svP0);   // sv0 == avg_hh(layer0)
    mean1_k <<<dim3(B_,16), 256, 0, stream>>>(cs0, mpart);
    mean2_k <<<B_,          256, 0, stream>>>(mpart, scP0);

    const float *hin = hh0, *cin = cs0;
    float *hout = hhA, *cout = csA;
    float *svin = svP0, *scin = scP0, *svout = svP1, *scout = scP1;

    for (int l=0; l<2; ++l){
        const float* avgp;
        if (l == 0){
            avgp = svin;            // mean(hh0) == initial sv
        } else {
            mean1_k<<<dim3(B_,16), 256, 0, stream>>>(hin, mpart);
            mean2_k<<<B_,          256, 0, stream>>>(mpart, avgh);
            avgp = avgh;
        }
        mv5_k   <<<dim3(5,B_), 256, 0, stream>>>(svin, avgp, Wfg_g, Wfg_h, Wog_g,
                                                 Wog_h, Wfgi_g, res5);
        comb_k  <<<B_, 256, 0, stream>>>(res5, b_fg, gbias, b_fgi, fhg, ogg, svg);
        buildx_k<<<M_, 256, 0, stream>>>(hin, wv, X);
        mgemm_k<0><<<dim3(2,128), 256, 0, stream>>>(X+512, WfgiT, fgih, nullptr,
                                                    H_, KBIG, H_, H_);
        scorep_k<<<dim3(32,B_), 256, 0, stream>>>(fgih, svg, cin, part);
        newscs_k<<<B_, 256, 0, stream>>>(part, fhg, ogg, scin, scout, svout);
        gterm_k <<<dim3(7,B_), 256, 0, stream>>>(svout, Wg, gbias, gt);
        mgemm_k<1><<<dim3(14,128), 256, 0, stream>>>(X, WT, pre, gt,
                                                     KBIG, KBIG, KBIG, NB);
        gates_k <<<M_/4, 256, 0, stream>>>(pre, cin, scin, hout, cout);
        hin = hout; cin = cout;
        hout = (l==0) ? hhB : hhA;
        cout = (l==0) ? csB : csA;
        float* q;
        q = svin; svin = svout; svout = q;
        q = scin; scin = scout; scout = q;
    }
    mean1_k<<<dim3(B_,16), 256, 0, stream>>>(hin, mpart);
    mean2_k<<<B_,          256, 0, stream>>>(mpart, avgh);
    head_k <<<B_, 256, 0, stream>>>(avgh, svin, W1, b1, Wout, bout, (float*)d_out);
}